// Round 15
// baseline (191.937 us; speedup 1.0000x reference)
//
#include <hip/hip_runtime.h>
#include <stdint.h>

#define N_NODES 100000
#define N_EDGES 1600000
#define D_FEAT  512
#define HIDDEN  64
#define N_CLASS 16
#define CAP     64          // fixed slot capacity per node (max in-deg ~45)
#define NBKT    196         // buckets of 512 nodes (dst>>9)
#define BCAP    10240       // per-bucket edge capacity (avg ~8163, >12 sigma margin)
#define EPB     4096        // edges per pass-1 block
#define NWG1    ((N_EDGES + EPB - 1) / EPB)   // 391
#define GEMM1_BLKS ((N_NODES + 127) / 128)    // 782

typedef __bf16 bf16_t;
typedef bf16_t bf16x8 __attribute__((ext_vector_type(8)));
typedef float  f32x4  __attribute__((ext_vector_type(4)));

// ---------------- threefry2x32-20, key = (0, 42)  (jax.random.key(42)) ------
__device__ __forceinline__ unsigned rotl32(unsigned x, int d) {
    return (x << d) | (x >> (32 - d));
}
__device__ __forceinline__ void tf_round(unsigned& x0, unsigned& x1, int r) {
    x0 += x1; x1 = rotl32(x1, r); x1 ^= x0;
}
__device__ __forceinline__ uint2 threefry_0_42(unsigned c0, unsigned c1) {
    const unsigned ks0 = 0u, ks1 = 42u, ks2 = 0x1BD11BDAu ^ 0u ^ 42u;
    unsigned x0 = c0 + ks0, x1 = c1 + ks1;
    tf_round(x0,x1,13); tf_round(x0,x1,15); tf_round(x0,x1,26); tf_round(x0,x1,6);
    x0 += ks1; x1 += ks2 + 1u;
    tf_round(x0,x1,17); tf_round(x0,x1,29); tf_round(x0,x1,16); tf_round(x0,x1,24);
    x0 += ks2; x1 += ks0 + 2u;
    tf_round(x0,x1,13); tf_round(x0,x1,15); tf_round(x0,x1,26); tf_round(x0,x1,6);
    x0 += ks0; x1 += ks1 + 3u;
    tf_round(x0,x1,17); tf_round(x0,x1,29); tf_round(x0,x1,16); tf_round(x0,x1,24);
    x0 += ks1; x1 += ks2 + 4u;
    tf_round(x0,x1,13); tf_round(x0,x1,15); tf_round(x0,x1,26); tf_round(x0,x1,6);
    x0 += ks2; x1 += ks0 + 5u;
    return make_uint2(x0, x1);
}

// ---- fused kernel 1: blocks [0,128) prep W1->Wfg ; blocks [128,..) bin edges
__launch_bounds__(256)
__global__ void k_prep_bin(const float* __restrict__ W1, bf16_t* __restrict__ Wfg,
                           const int* __restrict__ src, const int* __restrict__ dst,
                           const float* __restrict__ w,
                           int* __restrict__ bucket_cursor, int2* __restrict__ bkt) {
    __shared__ int hist[NBKT];
    __shared__ int binbase[NBKT];
    int tid = threadIdx.x;
    int bid = blockIdx.x;
    if (bid < 128) {
        int e = bid * 256 + tid;
        int k = e >> 6, col = e & 63;
        int kstep = k >> 5, gg = (k >> 3) & 3, e8 = k & 7;
        int cf = col >> 4, lane = (col & 15) | (gg << 4);
        Wfg[(((kstep << 2) + cf) << 9) + (lane << 3) + e8] = (bf16_t)W1[e];
        return;
    }
    int b0 = bid - 128;
    int c4 = b0 * (EPB / 4);                    // int4 base index
    for (int t = tid; t < NBKT; t += 256) hist[t] = 0;
    __syncthreads();
    int rk[16]; int dd[16];
    #pragma unroll
    for (int i = 0; i < EPB / 1024; ++i) {
        int e4 = c4 + tid + 256 * i;
        if (e4 * 4 < N_EDGES) {
            int4 d = ((const int4*)dst)[e4];
            dd[4*i+0] = d.x; dd[4*i+1] = d.y; dd[4*i+2] = d.z; dd[4*i+3] = d.w;
            rk[4*i+0] = atomicAdd(&hist[d.x >> 9], 1);
            rk[4*i+1] = atomicAdd(&hist[d.y >> 9], 1);
            rk[4*i+2] = atomicAdd(&hist[d.z >> 9], 1);
            rk[4*i+3] = atomicAdd(&hist[d.w >> 9], 1);
        }
    }
    __syncthreads();
    for (int t = tid; t < NBKT; t += 256)
        binbase[t] = hist[t] ? atomicAdd(&bucket_cursor[t], hist[t]) : 0;
    __syncthreads();
    #pragma unroll
    for (int i = 0; i < EPB / 1024; ++i) {
        int e4 = c4 + tid + 256 * i;
        if (e4 * 4 < N_EDGES) {
            int4 s  = ((const int4*)src)[e4];
            int4 wv = ((const int4*)w)[e4];
            int ss[4] = {s.x, s.y, s.z, s.w};
            int ww[4] = {wv.x, wv.y, wv.z, wv.w};
            #pragma unroll
            for (int q = 0; q < 4; ++q) {
                int d = dd[4*i+q];
                int b = d >> 9;
                int pos = binbase[b] + rk[4*i+q];
                if (pos < BCAP)
                    bkt[(size_t)b * BCAP + pos] =
                        make_int2(ss[q] | ((d & 511) << 17), ww[q]);
            }
        }
    }
}

// ---- fused kernel 2: blocks [0,NBKT) build slots+dis ; rest = gemm1 -------
// gemm1 (independent of build): h1[100000,64] = bf16(x @ W1)  (NO dis fold,
// so it can run concurrently with build). agg1 re-applies dis per edge.
__launch_bounds__(256)
__global__ void k_build_gemm1(const int* __restrict__ bucket_cursor,
                              const int2* __restrict__ bkt,
                              int2* __restrict__ slots, int* __restrict__ cursor,
                              float* __restrict__ dis,
                              const float* __restrict__ x,
                              const bf16_t* __restrict__ Wfg,
                              bf16_t* __restrict__ h1) {
    __shared__ __align__(16) char smem[32768];
    int tid = threadIdx.x;
    int bid = blockIdx.x;
    if (bid < NBKT) {
        int* cur  = (int*)smem;
        float* dg = (float*)(smem + 2048);
        int b = bid;
        cur[tid] = 0; cur[tid + 256] = 0;
        dg[tid] = 0.f; dg[tid + 256] = 0.f;
        __syncthreads();
        int cnt = bucket_cursor[b]; if (cnt > BCAP) cnt = BCAP;
        for (int e = tid; e < cnt; e += 256) {
            int2 p = bkt[(size_t)b * BCAP + e];
            int dl = ((unsigned)p.x) >> 17;
            int s  = p.x & 0x1FFFF;
            int rank = atomicAdd(&cur[dl], 1);
            if (rank < CAP)
                slots[((((size_t)b << 9) | dl) << 6) + rank] = make_int2(s, p.y);
            atomicAdd(&dg[dl], __int_as_float(p.y));
        }
        __syncthreads();
        #pragma unroll
        for (int t = 0; t < 2; ++t) {
            int loc = tid + 256 * t;
            int node = (b << 9) + loc;
            if (node < N_NODES) {
                cursor[node] = cur[loc];
                dis[node] = rsqrtf(dg[loc] + 1.0f);   // +1 = self-loop weight
            }
        }
        return;
    }
    // ---- gemm1 (no dis fold) ----
    bf16_t* Wf = (bf16_t*)smem;    // 32 KB: [t2:8][cf:4][lane:64][e:8]
    int gb = bid - NBKT;
    int w = tid >> 6, l = tid & 63;
    int r = l & 15, g = l >> 4;
    int wrow = gb * 128 + w * 32;
    f32x4 acc[2][4] = {};
    const float* xp0 = x + (size_t)(wrow + r) * D_FEAT + 8 * g;
    const float* xp1 = x + (size_t)(wrow + 16 + r) * D_FEAT + 8 * g;
    bool ok0 = (wrow + r) < N_NODES;
    bool ok1 = (wrow + 16 + r) < N_NODES;

    #pragma unroll
    for (int h = 0; h < 2; ++h) {
        if (h) __syncthreads();
        {
            const int4* sW = (const int4*)(Wfg + h * 16384);
            int4* dW = (int4*)Wf;
            #pragma unroll
            for (int t = 0; t < 8; ++t) dW[tid + 256 * t] = sW[tid + 256 * t];
        }
        __syncthreads();
        #pragma unroll
        for (int t2 = 0; t2 < 8; ++t2) {
            int t = h * 8 + t2;
            float4 p0 = make_float4(0.f,0.f,0.f,0.f), q0 = p0, p1 = p0, q1 = p0;
            if (ok0) {
                p0 = *(const float4*)(xp0 + t * 32);
                q0 = *(const float4*)(xp0 + t * 32 + 4);
            }
            if (ok1) {
                p1 = *(const float4*)(xp1 + t * 32);
                q1 = *(const float4*)(xp1 + t * 32 + 4);
            }
            bf16x8 a0, a1;
            a0[0]=(bf16_t)p0.x; a0[1]=(bf16_t)p0.y; a0[2]=(bf16_t)p0.z; a0[3]=(bf16_t)p0.w;
            a0[4]=(bf16_t)q0.x; a0[5]=(bf16_t)q0.y; a0[6]=(bf16_t)q0.z; a0[7]=(bf16_t)q0.w;
            a1[0]=(bf16_t)p1.x; a1[1]=(bf16_t)p1.y; a1[2]=(bf16_t)p1.z; a1[3]=(bf16_t)p1.w;
            a1[4]=(bf16_t)q1.x; a1[5]=(bf16_t)q1.y; a1[6]=(bf16_t)q1.z; a1[7]=(bf16_t)q1.w;
            #pragma unroll
            for (int cf = 0; cf < 4; ++cf) {
                bf16x8 b = *(const bf16x8*)&Wf[(((t2 << 2) + cf) << 9) + (l << 3)];
                acc[0][cf] = __builtin_amdgcn_mfma_f32_16x16x32_bf16(a0, b, acc[0][cf], 0, 0, 0);
                acc[1][cf] = __builtin_amdgcn_mfma_f32_16x16x32_bf16(a1, b, acc[1][cf], 0, 0, 0);
            }
        }
    }
    // C/D layout: col = lane&15, row = 4*(lane>>4) + reg
    #pragma unroll
    for (int rf = 0; rf < 2; ++rf)
        #pragma unroll
        for (int cf = 0; cf < 4; ++cf)
            #pragma unroll
            for (int q = 0; q < 4; ++q) {
                int row = wrow + rf * 16 + 4 * g + q;
                int col = cf * 16 + r;
                if (row < N_NODES) h1[(size_t)row * HIDDEN + col] = (bf16_t)acc[rf][cf][q];
            }
}

// ---- fused agg1 + bias + relu + dropout + gemm2 (8-deep gather pipeline) --
// h1 is UNfolded; dis[s] gathered per edge, batched with the row gathers
// (independent loads -> amortized latency). di factored out, applied at end.
__launch_bounds__(256)
__global__ void k_agg1(const bf16_t* __restrict__ h1, const int2* __restrict__ slots,
                       const int* __restrict__ cursor, const float* __restrict__ dis,
                       const float* __restrict__ b1, const float* __restrict__ W2,
                       bf16_t* __restrict__ g) {
    __shared__ float W2s[HIDDEN * 17];   // padded rows
    __shared__ float h2s[4][HIDDEN];
    int tid = threadIdx.x;
    #pragma unroll
    for (int t = 0; t < 4; ++t) {
        int e = tid + 256 * t;
        W2s[(e >> 4) * 17 + (e & 15)] = W2[e];
    }
    int i = (blockIdx.x * blockDim.x + tid) >> 6;  // node id
    int l = tid & 63;
    int w = tid >> 6;
    int h = l >> 5, s32 = l & 31;
    float di = (i < N_NODES) ? dis[i] : 0.f;
    if (i < N_NODES) {
        int cnt = cursor[i]; cnt = cnt > CAP ? CAP : cnt;
        const int2* sl = &slots[(size_t)i << 6];
        float a0 = 0.f, a1 = 0.f;
        float c0 = 0.f, c1 = 0.f;   // second accumulator pair (MLP)
        if (h == 0) {   // self loop: di * h1[i] (one more di applied at end)
            unsigned v = *(const unsigned*)&h1[(size_t)i * HIDDEN + 2 * s32];
            a0 = di * __uint_as_float(v << 16);
            a1 = di * __uint_as_float(v & 0xffff0000u);
        }
        int p = h;
        // 8-deep batch per half: 8 slots + 8 dis + 8 rows, all independent
        for (; p + 14 < cnt; p += 16) {
            int2 e0 = sl[p],      e1 = sl[p + 2],  e2 = sl[p + 4],  e3 = sl[p + 6];
            int2 e4 = sl[p + 8],  e5 = sl[p + 10], e6 = sl[p + 12], e7 = sl[p + 14];
            float d0 = dis[e0.x], d1 = dis[e1.x], d2 = dis[e2.x], d3 = dis[e3.x];
            float d4 = dis[e4.x], d5 = dis[e5.x], d6 = dis[e6.x], d7 = dis[e7.x];
            unsigned v0 = *(const unsigned*)&h1[(size_t)e0.x * HIDDEN + 2 * s32];
            unsigned v1 = *(const unsigned*)&h1[(size_t)e1.x * HIDDEN + 2 * s32];
            unsigned v2 = *(const unsigned*)&h1[(size_t)e2.x * HIDDEN + 2 * s32];
            unsigned v3 = *(const unsigned*)&h1[(size_t)e3.x * HIDDEN + 2 * s32];
            unsigned v4 = *(const unsigned*)&h1[(size_t)e4.x * HIDDEN + 2 * s32];
            unsigned v5 = *(const unsigned*)&h1[(size_t)e5.x * HIDDEN + 2 * s32];
            unsigned v6 = *(const unsigned*)&h1[(size_t)e6.x * HIDDEN + 2 * s32];
            unsigned v7 = *(const unsigned*)&h1[(size_t)e7.x * HIDDEN + 2 * s32];
            float n0 = d0 * __int_as_float(e0.y), n1 = d1 * __int_as_float(e1.y);
            float n2 = d2 * __int_as_float(e2.y), n3 = d3 * __int_as_float(e3.y);
            float n4 = d4 * __int_as_float(e4.y), n5 = d5 * __int_as_float(e5.y);
            float n6 = d6 * __int_as_float(e6.y), n7 = d7 * __int_as_float(e7.y);
            a0 += n0 * __uint_as_float(v0 << 16);
            a1 += n0 * __uint_as_float(v0 & 0xffff0000u);
            c0 += n1 * __uint_as_float(v1 << 16);
            c1 += n1 * __uint_as_float(v1 & 0xffff0000u);
            a0 += n2 * __uint_as_float(v2 << 16);
            a1 += n2 * __uint_as_float(v2 & 0xffff0000u);
            c0 += n3 * __uint_as_float(v3 << 16);
            c1 += n3 * __uint_as_float(v3 & 0xffff0000u);
            a0 += n4 * __uint_as_float(v4 << 16);
            a1 += n4 * __uint_as_float(v4 & 0xffff0000u);
            c0 += n5 * __uint_as_float(v5 << 16);
            c1 += n5 * __uint_as_float(v5 & 0xffff0000u);
            a0 += n6 * __uint_as_float(v6 << 16);
            a1 += n6 * __uint_as_float(v6 & 0xffff0000u);
            c0 += n7 * __uint_as_float(v7 << 16);
            c1 += n7 * __uint_as_float(v7 & 0xffff0000u);
        }
        // 4-deep cleanup
        for (; p + 6 < cnt; p += 8) {
            int2 e0 = sl[p], e1 = sl[p + 2], e2 = sl[p + 4], e3 = sl[p + 6];
            float d0 = dis[e0.x], d1 = dis[e1.x], d2 = dis[e2.x], d3 = dis[e3.x];
            unsigned v0 = *(const unsigned*)&h1[(size_t)e0.x * HIDDEN + 2 * s32];
            unsigned v1 = *(const unsigned*)&h1[(size_t)e1.x * HIDDEN + 2 * s32];
            unsigned v2 = *(const unsigned*)&h1[(size_t)e2.x * HIDDEN + 2 * s32];
            unsigned v3 = *(const unsigned*)&h1[(size_t)e3.x * HIDDEN + 2 * s32];
            float n0 = d0 * __int_as_float(e0.y), n1 = d1 * __int_as_float(e1.y);
            float n2 = d2 * __int_as_float(e2.y), n3 = d3 * __int_as_float(e3.y);
            a0 += n0 * __uint_as_float(v0 << 16);
            a1 += n0 * __uint_as_float(v0 & 0xffff0000u);
            c0 += n1 * __uint_as_float(v1 << 16);
            c1 += n1 * __uint_as_float(v1 & 0xffff0000u);
            a0 += n2 * __uint_as_float(v2 << 16);
            a1 += n2 * __uint_as_float(v2 & 0xffff0000u);
            c0 += n3 * __uint_as_float(v3 << 16);
            c1 += n3 * __uint_as_float(v3 & 0xffff0000u);
        }
        for (; p < cnt; p += 2) {
            int2 e0 = sl[p];
            float n = dis[e0.x] * __int_as_float(e0.y);
            unsigned v = *(const unsigned*)&h1[(size_t)e0.x * HIDDEN + 2 * s32];
            a0 += n * __uint_as_float(v << 16);
            a1 += n * __uint_as_float(v & 0xffff0000u);
        }
        a0 += c0; a1 += c1;
        a0 += __shfl_xor(a0, 32);
        a1 += __shfl_xor(a1, 32);
        int f = 2 * s32 + h;
        float av = di * (h ? a1 : a0) + b1[f];
        av = fmaxf(av, 0.f);
        unsigned idx = (unsigned)i * HIDDEN + f;
        uint2 rr = threefry_0_42(0u, idx);
        h2s[w][f] = ((rr.x ^ rr.y) & 0x80000000u) ? 0.f : av * 2.f;
    } else {
        h2s[w][2 * s32 + h] = 0.f;
    }
    __syncthreads();
    // phase 2: g'[node][j] = dis[node] * sum_f h2[f] * W2[f][j]  (bf16 store)
    int j = tid & 15, q = (tid >> 4) & 3;
    int node = blockIdx.x * 4 + w;   // == i
    float pk = 0.f;
    #pragma unroll
    for (int ff = 0; ff < 16; ++ff) {
        int fr = q * 16 + ff;
        pk += h2s[w][fr] * W2s[fr * 17 + j];
    }
    pk += __shfl_xor(pk, 16, 64);
    pk += __shfl_xor(pk, 32, 64);
    if (q == 0 && node < N_NODES) g[(size_t)node * N_CLASS + j] = (bf16_t)(di * pk);
}

// ---- agg2 + bias + log_softmax + both outputs (8-deep gather pipeline) ----
__launch_bounds__(256)
__global__ void k_out(const bf16_t* __restrict__ g, const int2* __restrict__ slots,
                      const int* __restrict__ cursor, const float* __restrict__ dis,
                      const float* __restrict__ b2, float* __restrict__ out) {
    int i = (blockIdx.x * blockDim.x + threadIdx.x) >> 4;  // node id
    int j = threadIdx.x & 15;
    if (i >= N_NODES) return;
    float di = dis[i];
    float acc = (float)g[(size_t)i * N_CLASS + j];   // self loop, w=1
    float acc2 = 0.f;
    int cnt = cursor[i]; cnt = cnt > CAP ? CAP : cnt;
    const int2* sl = &slots[(size_t)i << 6];
    int p = 0;
    for (; p + 8 <= cnt; p += 8) {
        int2 e0 = sl[p],     e1 = sl[p + 1], e2 = sl[p + 2], e3 = sl[p + 3];
        int2 e4 = sl[p + 4], e5 = sl[p + 5], e6 = sl[p + 6], e7 = sl[p + 7];
        float v0 = (float)g[(size_t)e0.x * N_CLASS + j];
        float v1 = (float)g[(size_t)e1.x * N_CLASS + j];
        float v2 = (float)g[(size_t)e2.x * N_CLASS + j];
        float v3 = (float)g[(size_t)e3.x * N_CLASS + j];
        float v4 = (float)g[(size_t)e4.x * N_CLASS + j];
        float v5 = (float)g[(size_t)e5.x * N_CLASS + j];
        float v6 = (float)g[(size_t)e6.x * N_CLASS + j];
        float v7 = (float)g[(size_t)e7.x * N_CLASS + j];
        acc  += __int_as_float(e0.y) * v0 + __int_as_float(e1.y) * v1
              + __int_as_float(e2.y) * v2 + __int_as_float(e3.y) * v3;
        acc2 += __int_as_float(e4.y) * v4 + __int_as_float(e5.y) * v5
              + __int_as_float(e6.y) * v6 + __int_as_float(e7.y) * v7;
    }
    for (; p + 4 <= cnt; p += 4) {
        int2 e0 = sl[p], e1 = sl[p + 1], e2 = sl[p + 2], e3 = sl[p + 3];
        float v0 = (float)g[(size_t)e0.x * N_CLASS + j];
        float v1 = (float)g[(size_t)e1.x * N_CLASS + j];
        float v2 = (float)g[(size_t)e2.x * N_CLASS + j];
        float v3 = (float)g[(size_t)e3.x * N_CLASS + j];
        acc  += __int_as_float(e0.y) * v0 + __int_as_float(e1.y) * v1;
        acc2 += __int_as_float(e2.y) * v2 + __int_as_float(e3.y) * v3;
    }
    for (; p < cnt; ++p) {
        int2 e0 = sl[p];
        acc += __int_as_float(e0.y) * (float)g[(size_t)e0.x * N_CLASS + j];
    }
    acc += acc2;
    acc = di * acc + b2[j];
    float xo = acc;
    float m = acc;
    #pragma unroll
    for (int d = 1; d < 16; d <<= 1) m = fmaxf(m, __shfl_xor(m, d, 16));
    float ex = expf(acc - m);
    float s = ex;
    #pragma unroll
    for (int d = 1; d < 16; d <<= 1) s += __shfl_xor(s, d, 16);
    float ls = (acc - m) - logf(s);
    out[(size_t)i * N_CLASS + j] = ls;
    out[(size_t)N_NODES * N_CLASS + (size_t)i * N_CLASS + j] = xo;
}

// ---------------------------------------------------------------------------
extern "C" void kernel_launch(void* const* d_in, const int* in_sizes, int n_in,
                              void* d_out, int out_size, void* d_ws, size_t ws_size,
                              hipStream_t stream) {
    const float* x  = (const float*)d_in[0];
    const int*   ei = (const int*)d_in[1];
    const float* ew = (const float*)d_in[2];
    const float* W1 = (const float*)d_in[3];
    const float* b1 = (const float*)d_in[4];
    const float* W2 = (const float*)d_in[5];
    const float* b2 = (const float*)d_in[6];
    float* out = (float*)d_out;
    const int* src = ei;
    const int* dst = ei + N_EDGES;

    size_t off = 0;
    char* wsb = (char*)d_ws;
    auto alloc = [&](size_t n) -> char* {
        char* p = wsb + off;
        off = (off + n + 255) & ~(size_t)255;
        return p;
    };
    int*    cursor = (int*)   alloc((size_t)N_NODES * 4);
    float*  dis    = (float*) alloc((size_t)N_NODES * 4);
    int*    bcur   = (int*)   alloc(NBKT * 4);
    bf16_t* Wfg    = (bf16_t*)alloc(32768 * 2);                  // 64 KB
    int2*   slots  = (int2*)  alloc((size_t)N_NODES * CAP * 8);  // 51.2 MB
    bf16_t* h1     = (bf16_t*)alloc((size_t)N_NODES * HIDDEN * 2); // 12.8 MB
    int2*   bkt    = (int2*)  alloc((size_t)NBKT * BCAP * 8);    // 16.1 MB
    bf16_t* g      = (bf16_t*)alloc((size_t)N_NODES * N_CLASS * 2); // 3.2 MB

    hipMemsetAsync(bcur, 0, NBKT * 4, stream);

    k_prep_bin   <<<128 + NWG1, 256, 0, stream>>>(W1, Wfg, src, dst, ew, bcur, bkt);
    k_build_gemm1<<<NBKT + GEMM1_BLKS, 256, 0, stream>>>(bcur, bkt, slots, cursor, dis,
                                                         x, Wfg, h1);
    k_agg1       <<<(N_NODES + 3) / 4, 256, 0, stream>>>(h1, slots, cursor, dis, b1, W2, g);
    k_out        <<<(N_NODES * 16 + 255) / 256, 256, 0, stream>>>(g, slots, cursor, dis, b2, out);
}

// Round 17
// 185.004 us; speedup vs baseline: 1.0375x; 1.0375x over previous
//
#include <hip/hip_runtime.h>
#include <stdint.h>

#define N_NODES 100000
#define N_EDGES 1600000
#define D_FEAT  512
#define HIDDEN  64
#define N_CLASS 16
#define CAP     64          // fixed slot capacity per node (max in-deg ~45)
#define NBKT    196         // buckets of 512 nodes (dst>>9)
#define BCAP    10240       // per-bucket edge capacity (avg ~8163, >12 sigma margin)
#define EPB     4096        // edges per pass-1 block
#define NWG1    ((N_EDGES + EPB - 1) / EPB)   // 391
#define GEMM1_BLKS ((N_NODES + 127) / 128)    // 782

typedef __bf16 bf16_t;
typedef bf16_t bf16x8 __attribute__((ext_vector_type(8)));
typedef float  f32x4  __attribute__((ext_vector_type(4)));

// ---------------- threefry2x32-20, key = (0, 42)  (jax.random.key(42)) ------
__device__ __forceinline__ unsigned rotl32(unsigned x, int d) {
    return (x << d) | (x >> (32 - d));
}
__device__ __forceinline__ void tf_round(unsigned& x0, unsigned& x1, int r) {
    x0 += x1; x1 = rotl32(x1, r); x1 ^= x0;
}
__device__ __forceinline__ uint2 threefry_0_42(unsigned c0, unsigned c1) {
    const unsigned ks0 = 0u, ks1 = 42u, ks2 = 0x1BD11BDAu ^ 0u ^ 42u;
    unsigned x0 = c0 + ks0, x1 = c1 + ks1;
    tf_round(x0,x1,13); tf_round(x0,x1,15); tf_round(x0,x1,26); tf_round(x0,x1,6);
    x0 += ks1; x1 += ks2 + 1u;
    tf_round(x0,x1,17); tf_round(x0,x1,29); tf_round(x0,x1,16); tf_round(x0,x1,24);
    x0 += ks2; x1 += ks0 + 2u;
    tf_round(x0,x1,13); tf_round(x0,x1,15); tf_round(x0,x1,26); tf_round(x0,x1,6);
    x0 += ks0; x1 += ks1 + 3u;
    tf_round(x0,x1,17); tf_round(x0,x1,29); tf_round(x0,x1,16); tf_round(x0,x1,24);
    x0 += ks1; x1 += ks2 + 4u;
    tf_round(x0,x1,13); tf_round(x0,x1,15); tf_round(x0,x1,26); tf_round(x0,x1,6);
    x0 += ks2; x1 += ks0 + 5u;
    return make_uint2(x0, x1);
}

// ---- fused kernel 1: blocks [0,128) prep W1->Wfg ; blocks [128,..) bin edges
__launch_bounds__(256)
__global__ void k_prep_bin(const float* __restrict__ W1, bf16_t* __restrict__ Wfg,
                           const int* __restrict__ src, const int* __restrict__ dst,
                           const float* __restrict__ w,
                           int* __restrict__ bucket_cursor, int2* __restrict__ bkt) {
    __shared__ int hist[NBKT];
    __shared__ int binbase[NBKT];
    int tid = threadIdx.x;
    int bid = blockIdx.x;
    if (bid < 128) {
        int e = bid * 256 + tid;
        int k = e >> 6, col = e & 63;
        int kstep = k >> 5, gg = (k >> 3) & 3, e8 = k & 7;
        int cf = col >> 4, lane = (col & 15) | (gg << 4);
        Wfg[(((kstep << 2) + cf) << 9) + (lane << 3) + e8] = (bf16_t)W1[e];
        return;
    }
    int b0 = bid - 128;
    int c4 = b0 * (EPB / 4);                    // int4 base index
    for (int t = tid; t < NBKT; t += 256) hist[t] = 0;
    __syncthreads();
    int rk[16]; int dd[16];
    #pragma unroll
    for (int i = 0; i < EPB / 1024; ++i) {
        int e4 = c4 + tid + 256 * i;
        if (e4 * 4 < N_EDGES) {
            int4 d = ((const int4*)dst)[e4];
            dd[4*i+0] = d.x; dd[4*i+1] = d.y; dd[4*i+2] = d.z; dd[4*i+3] = d.w;
            rk[4*i+0] = atomicAdd(&hist[d.x >> 9], 1);
            rk[4*i+1] = atomicAdd(&hist[d.y >> 9], 1);
            rk[4*i+2] = atomicAdd(&hist[d.z >> 9], 1);
            rk[4*i+3] = atomicAdd(&hist[d.w >> 9], 1);
        }
    }
    __syncthreads();
    for (int t = tid; t < NBKT; t += 256)
        binbase[t] = hist[t] ? atomicAdd(&bucket_cursor[t], hist[t]) : 0;
    __syncthreads();
    #pragma unroll
    for (int i = 0; i < EPB / 1024; ++i) {
        int e4 = c4 + tid + 256 * i;
        if (e4 * 4 < N_EDGES) {
            int4 s  = ((const int4*)src)[e4];
            int4 wv = ((const int4*)w)[e4];
            int ss[4] = {s.x, s.y, s.z, s.w};
            int ww[4] = {wv.x, wv.y, wv.z, wv.w};
            #pragma unroll
            for (int q = 0; q < 4; ++q) {
                int d = dd[4*i+q];
                int b = d >> 9;
                int pos = binbase[b] + rk[4*i+q];
                if (pos < BCAP)
                    bkt[(size_t)b * BCAP + pos] =
                        make_int2(ss[q] | ((d & 511) << 17), ww[q]);
            }
        }
    }
}

// ---- per-bucket slot build + weighted degree + dis ------------------------
__launch_bounds__(256)
__global__ void k_build(const int* __restrict__ bucket_cursor, const int2* __restrict__ bkt,
                        int2* __restrict__ slots, int* __restrict__ cursor,
                        float* __restrict__ dis) {
    __shared__ int   cur[512];
    __shared__ float dg[512];
    int b = blockIdx.x, tid = threadIdx.x;
    cur[tid] = 0; cur[tid + 256] = 0;
    dg[tid] = 0.f; dg[tid + 256] = 0.f;
    __syncthreads();
    int cnt = bucket_cursor[b]; if (cnt > BCAP) cnt = BCAP;
    for (int e = tid; e < cnt; e += 256) {
        int2 p = bkt[(size_t)b * BCAP + e];
        int dl = ((unsigned)p.x) >> 17;
        int s  = p.x & 0x1FFFF;
        int rank = atomicAdd(&cur[dl], 1);
        if (rank < CAP)
            slots[((((size_t)b << 9) | dl) << 6) + rank] = make_int2(s, p.y);
        atomicAdd(&dg[dl], __int_as_float(p.y));
    }
    __syncthreads();
    #pragma unroll
    for (int t = 0; t < 2; ++t) {
        int loc = tid + 256 * t;
        int node = (b << 9) + loc;
        if (node < N_NODES) {
            cursor[node] = cur[loc];
            dis[node] = rsqrtf(dg[loc] + 1.0f);   // +1 = self-loop weight
        }
    }
}

// ---- GEMM1 (bf16 MFMA) with dis-folded output: h1'[s] = dis[s]*(x@W1)[s] ---
__launch_bounds__(256)
__global__ void k_gemm1(const float* __restrict__ x, const bf16_t* __restrict__ Wfg,
                        const float* __restrict__ dis, bf16_t* __restrict__ h1) {
    __shared__ bf16_t Wf[16384];   // 32 KB: [t2:8][cf:4][lane:64][e:8]
    int tid = threadIdx.x;
    int w = tid >> 6, l = tid & 63;
    int r = l & 15, g = l >> 4;
    int wrow = blockIdx.x * 128 + w * 32;
    f32x4 acc[2][4] = {};
    const float* xp0 = x + (size_t)(wrow + r) * D_FEAT + 8 * g;
    const float* xp1 = x + (size_t)(wrow + 16 + r) * D_FEAT + 8 * g;
    bool ok0 = (wrow + r) < N_NODES;
    bool ok1 = (wrow + 16 + r) < N_NODES;

    #pragma unroll
    for (int h = 0; h < 2; ++h) {
        if (h) __syncthreads();
        {
            const int4* sW = (const int4*)(Wfg + h * 16384);
            int4* dW = (int4*)Wf;
            #pragma unroll
            for (int t = 0; t < 8; ++t) dW[tid + 256 * t] = sW[tid + 256 * t];
        }
        __syncthreads();
        #pragma unroll
        for (int t2 = 0; t2 < 8; ++t2) {
            int t = h * 8 + t2;
            float4 p0 = make_float4(0.f,0.f,0.f,0.f), q0 = p0, p1 = p0, q1 = p0;
            if (ok0) {
                p0 = *(const float4*)(xp0 + t * 32);
                q0 = *(const float4*)(xp0 + t * 32 + 4);
            }
            if (ok1) {
                p1 = *(const float4*)(xp1 + t * 32);
                q1 = *(const float4*)(xp1 + t * 32 + 4);
            }
            bf16x8 a0, a1;
            a0[0]=(bf16_t)p0.x; a0[1]=(bf16_t)p0.y; a0[2]=(bf16_t)p0.z; a0[3]=(bf16_t)p0.w;
            a0[4]=(bf16_t)q0.x; a0[5]=(bf16_t)q0.y; a0[6]=(bf16_t)q0.z; a0[7]=(bf16_t)q0.w;
            a1[0]=(bf16_t)p1.x; a1[1]=(bf16_t)p1.y; a1[2]=(bf16_t)p1.z; a1[3]=(bf16_t)p1.w;
            a1[4]=(bf16_t)q1.x; a1[5]=(bf16_t)q1.y; a1[6]=(bf16_t)q1.z; a1[7]=(bf16_t)q1.w;
            #pragma unroll
            for (int cf = 0; cf < 4; ++cf) {
                bf16x8 b = *(const bf16x8*)&Wf[(((t2 << 2) + cf) << 9) + (l << 3)];
                acc[0][cf] = __builtin_amdgcn_mfma_f32_16x16x32_bf16(a0, b, acc[0][cf], 0, 0, 0);
                acc[1][cf] = __builtin_amdgcn_mfma_f32_16x16x32_bf16(a1, b, acc[1][cf], 0, 0, 0);
            }
        }
    }
    // C/D layout: col = lane&15, row = 4*(lane>>4) + reg ; fold dis[row]
    #pragma unroll
    for (int rf = 0; rf < 2; ++rf)
        #pragma unroll
        for (int q = 0; q < 4; ++q) {
            int row = wrow + rf * 16 + 4 * g + q;
            if (row < N_NODES) {
                float dv = dis[row];
                #pragma unroll
                for (int cf = 0; cf < 4; ++cf)
                    h1[(size_t)row * HIDDEN + cf * 16 + r] = (bf16_t)(dv * acc[rf][cf][q]);
            }
        }
}

// ---- fused agg1 + bias + relu + dropout + gemm2 (4-deep gather pipeline) --
__launch_bounds__(256)
__global__ void k_agg1(const bf16_t* __restrict__ h1, const int2* __restrict__ slots,
                       const int* __restrict__ cursor, const float* __restrict__ dis,
                       const float* __restrict__ b1, const float* __restrict__ W2,
                       bf16_t* __restrict__ g) {
    __shared__ float W2s[HIDDEN * 17];   // padded rows
    __shared__ float h2s[4][HIDDEN];
    int tid = threadIdx.x;
    #pragma unroll
    for (int t = 0; t < 4; ++t) {
        int e = tid + 256 * t;
        W2s[(e >> 4) * 17 + (e & 15)] = W2[e];
    }
    int i = (blockIdx.x * blockDim.x + tid) >> 6;  // node id
    int l = tid & 63;
    int w = tid >> 6;
    int h = l >> 5, s32 = l & 31;
    float di = (i < N_NODES) ? dis[i] : 0.f;
    if (i < N_NODES) {
        int cnt = cursor[i]; cnt = cnt > CAP ? CAP : cnt;
        const int2* sl = &slots[(size_t)i << 6];
        float a0 = 0.f, a1 = 0.f;
        float c0 = 0.f, c1 = 0.f;   // second accumulator pair (MLP)
        if (h == 0) {   // self loop: weight 1 on h1' (dis already folded)
            unsigned v = *(const unsigned*)&h1[(size_t)i * HIDDEN + 2 * s32];
            a0 = __uint_as_float(v << 16);
            a1 = __uint_as_float(v & 0xffff0000u);
        }
        int p = h;
        // 4-deep pipeline per half: batch 4 slot loads, then 4 gathers
        for (; p + 6 < cnt; p += 8) {
            int2 e0 = sl[p], e1 = sl[p + 2], e2 = sl[p + 4], e3 = sl[p + 6];
            float n0 = __int_as_float(e0.y), n1 = __int_as_float(e1.y);
            float n2 = __int_as_float(e2.y), n3 = __int_as_float(e3.y);
            unsigned v0 = *(const unsigned*)&h1[(size_t)e0.x * HIDDEN + 2 * s32];
            unsigned v1 = *(const unsigned*)&h1[(size_t)e1.x * HIDDEN + 2 * s32];
            unsigned v2 = *(const unsigned*)&h1[(size_t)e2.x * HIDDEN + 2 * s32];
            unsigned v3 = *(const unsigned*)&h1[(size_t)e3.x * HIDDEN + 2 * s32];
            a0 += n0 * __uint_as_float(v0 << 16);
            a1 += n0 * __uint_as_float(v0 & 0xffff0000u);
            c0 += n1 * __uint_as_float(v1 << 16);
            c1 += n1 * __uint_as_float(v1 & 0xffff0000u);
            a0 += n2 * __uint_as_float(v2 << 16);
            a1 += n2 * __uint_as_float(v2 & 0xffff0000u);
            c0 += n3 * __uint_as_float(v3 << 16);
            c1 += n3 * __uint_as_float(v3 & 0xffff0000u);
        }
        for (; p < cnt; p += 2) {
            int2 e0 = sl[p];
            float n = __int_as_float(e0.y);
            unsigned v = *(const unsigned*)&h1[(size_t)e0.x * HIDDEN + 2 * s32];
            a0 += n * __uint_as_float(v << 16);
            a1 += n * __uint_as_float(v & 0xffff0000u);
        }
        a0 += c0; a1 += c1;
        a0 += __shfl_xor(a0, 32);
        a1 += __shfl_xor(a1, 32);
        int f = 2 * s32 + h;
        float av = di * (h ? a1 : a0) + b1[f];
        av = fmaxf(av, 0.f);
        unsigned idx = (unsigned)i * HIDDEN + f;
        uint2 rr = threefry_0_42(0u, idx);
        h2s[w][f] = ((rr.x ^ rr.y) & 0x80000000u) ? 0.f : av * 2.f;
    } else {
        h2s[w][2 * s32 + h] = 0.f;
    }
    __syncthreads();
    // phase 2: g'[node][j] = dis[node] * sum_f h2[f] * W2[f][j]  (bf16 store)
    int j = tid & 15, q = (tid >> 4) & 3;
    int node = blockIdx.x * 4 + w;   // == i
    float pk = 0.f;
    #pragma unroll
    for (int ff = 0; ff < 16; ++ff) {
        int fr = q * 16 + ff;
        pk += h2s[w][fr] * W2s[fr * 17 + j];
    }
    pk += __shfl_xor(pk, 16, 64);
    pk += __shfl_xor(pk, 32, 64);
    if (q == 0 && node < N_NODES) g[(size_t)node * N_CLASS + j] = (bf16_t)(di * pk);
}

// ---- agg2 + bias + log_softmax + both outputs (8-deep gather pipeline) ----
__launch_bounds__(256)
__global__ void k_out(const bf16_t* __restrict__ g, const int2* __restrict__ slots,
                      const int* __restrict__ cursor, const float* __restrict__ dis,
                      const float* __restrict__ b2, float* __restrict__ out) {
    int i = (blockIdx.x * blockDim.x + threadIdx.x) >> 4;  // node id
    int j = threadIdx.x & 15;
    if (i >= N_NODES) return;
    float di = dis[i];
    float acc = (float)g[(size_t)i * N_CLASS + j];   // self loop, w=1
    float acc2 = 0.f;
    int cnt = cursor[i]; cnt = cnt > CAP ? CAP : cnt;
    const int2* sl = &slots[(size_t)i << 6];
    int p = 0;
    for (; p + 8 <= cnt; p += 8) {
        int2 e0 = sl[p],     e1 = sl[p + 1], e2 = sl[p + 2], e3 = sl[p + 3];
        int2 e4 = sl[p + 4], e5 = sl[p + 5], e6 = sl[p + 6], e7 = sl[p + 7];
        float v0 = (float)g[(size_t)e0.x * N_CLASS + j];
        float v1 = (float)g[(size_t)e1.x * N_CLASS + j];
        float v2 = (float)g[(size_t)e2.x * N_CLASS + j];
        float v3 = (float)g[(size_t)e3.x * N_CLASS + j];
        float v4 = (float)g[(size_t)e4.x * N_CLASS + j];
        float v5 = (float)g[(size_t)e5.x * N_CLASS + j];
        float v6 = (float)g[(size_t)e6.x * N_CLASS + j];
        float v7 = (float)g[(size_t)e7.x * N_CLASS + j];
        acc  += __int_as_float(e0.y) * v0 + __int_as_float(e1.y) * v1
              + __int_as_float(e2.y) * v2 + __int_as_float(e3.y) * v3;
        acc2 += __int_as_float(e4.y) * v4 + __int_as_float(e5.y) * v5
              + __int_as_float(e6.y) * v6 + __int_as_float(e7.y) * v7;
    }
    for (; p + 4 <= cnt; p += 4) {
        int2 e0 = sl[p], e1 = sl[p + 1], e2 = sl[p + 2], e3 = sl[p + 3];
        float v0 = (float)g[(size_t)e0.x * N_CLASS + j];
        float v1 = (float)g[(size_t)e1.x * N_CLASS + j];
        float v2 = (float)g[(size_t)e2.x * N_CLASS + j];
        float v3 = (float)g[(size_t)e3.x * N_CLASS + j];
        acc  += __int_as_float(e0.y) * v0 + __int_as_float(e1.y) * v1;
        acc2 += __int_as_float(e2.y) * v2 + __int_as_float(e3.y) * v3;
    }
    for (; p < cnt; ++p) {
        int2 e0 = sl[p];
        acc += __int_as_float(e0.y) * (float)g[(size_t)e0.x * N_CLASS + j];
    }
    acc += acc2;
    acc = di * acc + b2[j];
    float xo = acc;
    float m = acc;
    #pragma unroll
    for (int d = 1; d < 16; d <<= 1) m = fmaxf(m, __shfl_xor(m, d, 16));
    float ex = expf(acc - m);
    float s = ex;
    #pragma unroll
    for (int d = 1; d < 16; d <<= 1) s += __shfl_xor(s, d, 16);
    float ls = (acc - m) - logf(s);
    out[(size_t)i * N_CLASS + j] = ls;
    out[(size_t)N_NODES * N_CLASS + (size_t)i * N_CLASS + j] = xo;
}

// ---------------------------------------------------------------------------
extern "C" void kernel_launch(void* const* d_in, const int* in_sizes, int n_in,
                              void* d_out, int out_size, void* d_ws, size_t ws_size,
                              hipStream_t stream) {
    const float* x  = (const float*)d_in[0];
    const int*   ei = (const int*)d_in[1];
    const float* ew = (const float*)d_in[2];
    const float* W1 = (const float*)d_in[3];
    const float* b1 = (const float*)d_in[4];
    const float* W2 = (const float*)d_in[5];
    const float* b2 = (const float*)d_in[6];
    float* out = (float*)d_out;
    const int* src = ei;
    const int* dst = ei + N_EDGES;

    size_t off = 0;
    char* wsb = (char*)d_ws;
    auto alloc = [&](size_t n) -> char* {
        char* p = wsb + off;
        off = (off + n + 255) & ~(size_t)255;
        return p;
    };
    int*    cursor = (int*)   alloc((size_t)N_NODES * 4);
    float*  dis    = (float*) alloc((size_t)N_NODES * 4);
    int*    bcur   = (int*)   alloc(NBKT * 4);
    bf16_t* Wfg    = (bf16_t*)alloc(32768 * 2);                  // 64 KB
    int2*   slots  = (int2*)  alloc((size_t)N_NODES * CAP * 8);  // 51.2 MB
    bf16_t* h1     = (bf16_t*)alloc((size_t)N_NODES * HIDDEN * 2); // 12.8 MB
    int2*   bkt    = (int2*)  alloc((size_t)NBKT * BCAP * 8);    // 16.1 MB
    bf16_t* g      = (bf16_t*)alloc((size_t)N_NODES * N_CLASS * 2); // 3.2 MB

    hipMemsetAsync(bcur, 0, NBKT * 4, stream);

    k_prep_bin<<<128 + NWG1, 256, 0, stream>>>(W1, Wfg, src, dst, ew, bcur, bkt);
    k_build   <<<NBKT, 256, 0, stream>>>(bcur, bkt, slots, cursor, dis);
    k_gemm1   <<<GEMM1_BLKS, 256, 0, stream>>>(x, Wfg, dis, h1);
    k_agg1    <<<(N_NODES + 3) / 4, 256, 0, stream>>>(h1, slots, cursor, dis, b1, W2, g);
    k_out     <<<(N_NODES * 16 + 255) / 256, 256, 0, stream>>>(g, slots, cursor, dis, b2, out);
}